// Round 3
// baseline (2010.527 us; speedup 1.0000x reference)
//
#include <hip/hip_runtime.h>
#include <math.h>

// Problem constants
#define L4   4
#define CPL  1024
#define HID  1024
#define IND  512
#define MLPD 128
#define OUTD 512
#define G3   3072
#define ROWS 4096   // L4*CPL

typedef unsigned short u16;   // bf16 bits

__device__ __forceinline__ float b2f(u16 u) {
  return __uint_as_float(((unsigned int)u) << 16);
}
__device__ __forceinline__ u16 f2b(float f) {   // round-to-nearest-even
  unsigned int x = __float_as_uint(f);
  x += 0x7fffu + ((x >> 16) & 1u);
  return (u16)(x >> 16);
}
__device__ __forceinline__ float sigm(float v) { return 1.0f/(1.0f + expf(-v)); }

// ---- dual-dtype access helpers: f32 flag selects float32 vs bf16 layout ----
struct F4 { float x, y, z, w; };
__device__ __forceinline__ F4 ld4(const void* p, size_t i, bool f32) {
  F4 r;
  if (f32) {
    float4 v = *reinterpret_cast<const float4*>((const float*)p + i);
    r.x = v.x; r.y = v.y; r.z = v.z; r.w = v.w;
  } else {
    ushort4 v = *reinterpret_cast<const ushort4*>((const u16*)p + i);
    r.x = b2f(v.x); r.y = b2f(v.y); r.z = b2f(v.z); r.w = b2f(v.w);
  }
  return r;
}
__device__ __forceinline__ float ld1(const void* p, size_t i, bool f32) {
  return f32 ? ((const float*)p)[i] : b2f(((const u16*)p)[i]);
}
__device__ __forceinline__ void st1(void* p, size_t i, float v, bool f32) {
  if (f32) ((float*)p)[i] = v; else ((u16*)p)[i] = f2b(v);
}

// ---------------- detector + init ----------------
// x ~ N(0,1), 512 elements. If buffer is bf16: even u16s are real bf16 values,
// exponent field in [96,134] essentially always. If buffer is fp32: even u16s are
// low mantissa halves -> uniform random -> ~15% in band. Count over 256 samples.
__global__ void k_detect(const void* __restrict__ x, int* __restrict__ flag,
                         float* __restrict__ tsum) {
  int t = threadIdx.x;   // 256
  if (t < 64) tsum[t] = 0.0f;
  const u16* xu = (const u16*)x;
  unsigned u = xu[2*t];
  int e = (u >> 7) & 0xFF;
  int good = (e >= 96 && e <= 134) ? 1 : 0;
  __shared__ int cnt[256];
  cnt[t] = good;
  __syncthreads();
  for (int s = 128; s > 0; s >>= 1) { if (t < s) cnt[t] += cnt[t+s]; __syncthreads(); }
  if (t == 0) flag[0] = (cnt[0] < 200) ? 1 : 0;   // 1 = float32, 0 = bf16
}

// base[path][l][m] = b1 + sum_i x[i]*W1[l,i,m]
__global__ void k_base(const void* __restrict__ x, const void* __restrict__ eaW1,
                       const void* __restrict__ egW1, const void* __restrict__ eab1,
                       const void* __restrict__ egb1, const int* __restrict__ dflag,
                       float* __restrict__ base) {
  const bool f32 = dflag[0] != 0;
  int l = blockIdx.x, path = blockIdx.y, m = threadIdx.x;  // 4 x 2 blocks, 128 thr
  const void* W1 = path ? egW1 : eaW1;
  const void* b1 = path ? egb1 : eab1;
  float acc = ld1(b1, l*MLPD + m, f32);
  size_t wbase = (size_t)l*1536*MLPD + m;
  for (int i = 0; i < IND; ++i)
    acc += ld1(x, i, f32) * ld1(W1, wbase + (size_t)i*MLPD, f32);
  base[path*(L4*MLPD) + l*MLPD + m] = acc;
}

// ---------------- tiled GEMMs: BM=BN=64, BK=16, 256 thr, 4x4 micro-tile ----------------
#define BM 64
#define BN 64
#define BK 16

// Z = relu(base + H @ W1[512:,:])   output Z bf16 [4096, 256] (a-path | g-path)
__global__ __launch_bounds__(256) void k_z(
    const void* __restrict__ A, const void* __restrict__ eaW1, const void* __restrict__ egW1,
    const float* __restrict__ base, const int* __restrict__ dflag, u16* __restrict__ Z) {
  const bool f32 = dflag[0] != 0;
  __shared__ float As[BK][BM];
  __shared__ float Bs[BK][BN];
  int t = threadIdx.x;
  int row0 = blockIdx.x * BM;
  int n0   = blockIdx.y * BN;          // 0,64,128,192
  int l    = row0 >> 10;
  int path = n0 >> 7;
  int mc0  = n0 & 127;
  const void* B = path ? egW1 : eaW1;
  size_t boff = (size_t)l*1536*MLPD + (size_t)IND*MLPD + mc0;
  int tx = t & 15, ty = t >> 4;
  int am = t >> 2, akq = (t & 3) * 4;
  int bk = t >> 4, bn = (t & 15) * 4;

  float acc[4][4];
  {
    float bv[4];
#pragma unroll
    for (int j = 0; j < 4; ++j)
      bv[j] = base[path*(L4*MLPD) + l*MLPD + mc0 + tx*4 + j];
#pragma unroll
    for (int i = 0; i < 4; ++i)
#pragma unroll
      for (int j = 0; j < 4; ++j) acc[i][j] = bv[j];
  }
  for (int k0 = 0; k0 < HID; k0 += BK) {
    F4 av = ld4(A, (size_t)(row0 + am)*HID + k0 + akq, f32);
    F4 bv = ld4(B, boff + (size_t)(k0 + bk)*MLPD + bn, f32);
    __syncthreads();
    As[akq+0][am] = av.x; As[akq+1][am] = av.y;
    As[akq+2][am] = av.z; As[akq+3][am] = av.w;
    Bs[bk][bn+0] = bv.x; Bs[bk][bn+1] = bv.y;
    Bs[bk][bn+2] = bv.z; Bs[bk][bn+3] = bv.w;
    __syncthreads();
#pragma unroll
    for (int kk = 0; kk < BK; ++kk) {
      float4 a4 = *reinterpret_cast<const float4*>(&As[kk][ty*4]);
      float4 b4 = *reinterpret_cast<const float4*>(&Bs[kk][tx*4]);
      float a[4] = {a4.x,a4.y,a4.z,a4.w};
      float b[4] = {b4.x,b4.y,b4.z,b4.w};
#pragma unroll
      for (int i = 0; i < 4; ++i)
#pragma unroll
        for (int j = 0; j < 4; ++j) acc[i][j] += a[i]*b[j];
    }
  }
#pragma unroll
  for (int i = 0; i < 4; ++i) {
    int r = row0 + ty*4 + i;
#pragma unroll
    for (int j = 0; j < 4; ++j) {
      float v = acc[i][j]; v = v > 0.0f ? v : 0.0f;
      Z[(size_t)r*256 + n0 + tx*4 + j] = f2b(v);
    }
  }
}

// OUT = Za@W2a - Zg@W2g + (b2a-b2g)   A = Z [4096,256] bf16, B = W2 [128,512] (NN)
__global__ __launch_bounds__(256) void k_out(
    const u16* __restrict__ Zb, const void* __restrict__ eaW2, const void* __restrict__ egW2,
    const void* __restrict__ eab2, const void* __restrict__ egb2,
    const int* __restrict__ dflag, u16* __restrict__ OUTm) {
  const bool f32 = dflag[0] != 0;
  __shared__ float As[BK][BM];
  __shared__ float Bs[BK][BN];
  int t = threadIdx.x;
  int row0 = blockIdx.x * BM;
  int n0   = blockIdx.y * BN;          // 0..448
  int l    = row0 >> 10;
  const u16* Ab = Zb + (size_t)row0 * 256;
  int tx = t & 15, ty = t >> 4;
  int am = t >> 2, akq = (t & 3) * 4;
  int bk = t >> 4, bn = (t & 15) * 4;

  float acc[4][4];
#pragma unroll
  for (int j = 0; j < 4; ++j) {
    int o = n0 + tx*4 + j;
    float bd = ld1(eab2, l*OUTD + o, f32) - ld1(egb2, l*OUTD + o, f32);
#pragma unroll
    for (int i = 0; i < 4; ++i) acc[i][j] = bd;
  }

  for (int ph = 0; ph < 2; ++ph) {
    const void* B = ph ? egW2 : eaW2;
    size_t boff = (size_t)l*MLPD*OUTD + n0;
    float sgn = ph ? -1.0f : 1.0f;
    for (int k0 = 0; k0 < MLPD; k0 += BK) {
      ushort4 av = *reinterpret_cast<const ushort4*>(Ab + (size_t)am*256 + ph*128 + k0 + akq);
      F4 bv = ld4(B, boff + (size_t)(k0 + bk)*OUTD + bn, f32);
      __syncthreads();
      As[akq+0][am] = b2f(av.x); As[akq+1][am] = b2f(av.y);
      As[akq+2][am] = b2f(av.z); As[akq+3][am] = b2f(av.w);
      Bs[bk][bn+0] = sgn*bv.x; Bs[bk][bn+1] = sgn*bv.y;
      Bs[bk][bn+2] = sgn*bv.z; Bs[bk][bn+3] = sgn*bv.w;
      __syncthreads();
#pragma unroll
      for (int kk = 0; kk < BK; ++kk) {
        float4 a4 = *reinterpret_cast<const float4*>(&As[kk][ty*4]);
        float4 b4 = *reinterpret_cast<const float4*>(&Bs[kk][tx*4]);
        float a[4] = {a4.x,a4.y,a4.z,a4.w};
        float b[4] = {b4.x,b4.y,b4.z,b4.w};
#pragma unroll
        for (int i = 0; i < 4; ++i)
#pragma unroll
          for (int j = 0; j < 4; ++j) acc[i][j] += a[i]*b[j];
      }
    }
  }
#pragma unroll
  for (int i = 0; i < 4; ++i) {
    int r = row0 + ty*4 + i;
#pragma unroll
    for (int j = 0; j < 4; ++j)
      OUTm[(size_t)r*OUTD + n0 + tx*4 + j] = f2b(acc[i][j]);
  }
}

// tension[row] = mean(out^2); tsum += sumsq(row)
__global__ void k_tension(const u16* __restrict__ OUTm, float* __restrict__ tension,
                          float* __restrict__ tsum) {
  int row = blockIdx.x, t = threadIdx.x;
  const u16* p = OUTm + (size_t)row*OUTD;
  float v0 = b2f(p[t]), v1 = b2f(p[t+256]);
  float s = v0*v0 + v1*v1;
#pragma unroll
  for (int off = 32; off > 0; off >>= 1) s += __shfl_down(s, off, 64);
  __shared__ float red[4];
  if ((t & 63) == 0) red[t >> 6] = s;
  __syncthreads();
  if (t == 0) {
    float tot = red[0] + red[1] + red[2] + red[3];
    tension[row] = tot * (1.0f/512.0f);
    atomicAdd(tsum, tot);
  }
}

// Fused GRU: i_r,i_z,i_n (OUT@Wih^T, K=512, + tension col) and h_r,h_z,h_n (H@Whh^T,
// K=1024), then gates -> new_h written into d_out hh region (dual-dtype store)
__global__ __launch_bounds__(256) void k_gru(
    const u16* __restrict__ OUTm, const void* __restrict__ H,
    const void* __restrict__ Wih, const void* __restrict__ Whh,
    const void* __restrict__ bih, const void* __restrict__ bhh,
    const float* __restrict__ tension, const int* __restrict__ dflag,
    void* __restrict__ outv) {
  const bool f32 = dflag[0] != 0;
  __shared__ float As[BK][BM];
  __shared__ float Bs[3][BK][BN];
  int t = threadIdx.x;
  int row0 = blockIdx.x * BM;
  int j0   = blockIdx.y * BN;
  int l    = row0 >> 10;
  size_t wihL = (size_t)l*G3*513;
  size_t whhL = (size_t)l*G3*HID;
  int tx = t & 15, ty = t >> 4;
  int am = t >> 2, akq = (t & 3) * 4;
  int bn_n = t >> 2, bkq = (t & 3) * 4;

  float acc[4][4][4];   // [band: r, z, i_n, h_n][i][j]
#pragma unroll
  for (int b = 0; b < 4; ++b)
#pragma unroll
    for (int i = 0; i < 4; ++i)
#pragma unroll
      for (int j = 0; j < 4; ++j) acc[b][i][j] = 0.0f;

  // ---- loop 1: A = OUT [4096,512] bf16, B rows = Wih (ld 513, scalar loads) ----
  for (int k0 = 0; k0 < OUTD; k0 += BK) {
    ushort4 av = *reinterpret_cast<const ushort4*>(OUTm + (size_t)(row0 + am)*OUTD + k0 + akq);
    float bv[3][4];
#pragma unroll
    for (int bnd = 0; bnd < 3; ++bnd) {
      size_t brow = wihL + (size_t)(bnd*1024 + j0 + bn_n)*513 + k0 + bkq;
#pragma unroll
      for (int i = 0; i < 4; ++i) bv[bnd][i] = ld1(Wih, brow + i, f32);
    }
    __syncthreads();
    As[akq+0][am] = b2f(av.x); As[akq+1][am] = b2f(av.y);
    As[akq+2][am] = b2f(av.z); As[akq+3][am] = b2f(av.w);
#pragma unroll
    for (int bnd = 0; bnd < 3; ++bnd)
#pragma unroll
      for (int i = 0; i < 4; ++i) Bs[bnd][bkq+i][bn_n] = bv[bnd][i];
    __syncthreads();
#pragma unroll
    for (int kk = 0; kk < BK; ++kk) {
      float4 a4 = *reinterpret_cast<const float4*>(&As[kk][ty*4]);
      float a[4] = {a4.x,a4.y,a4.z,a4.w};
#pragma unroll
      for (int bnd = 0; bnd < 3; ++bnd) {
        float4 b4 = *reinterpret_cast<const float4*>(&Bs[bnd][kk][tx*4]);
        float b[4] = {b4.x,b4.y,b4.z,b4.w};
#pragma unroll
        for (int i = 0; i < 4; ++i)
#pragma unroll
          for (int j = 0; j < 4; ++j) acc[bnd][i][j] += a[i]*b[j];
      }
    }
  }
  // ---- loop 2: A = H [4096,1024], B rows = Whh (ld 1024, vec loads) ----
  for (int k0 = 0; k0 < HID; k0 += BK) {
    F4 av = ld4(H, (size_t)(row0 + am)*HID + k0 + akq, f32);
    F4 bv[3];
#pragma unroll
    for (int bnd = 0; bnd < 3; ++bnd)
      bv[bnd] = ld4(Whh, whhL + (size_t)(bnd*1024 + j0 + bn_n)*HID + k0 + bkq, f32);
    __syncthreads();
    As[akq+0][am] = av.x; As[akq+1][am] = av.y;
    As[akq+2][am] = av.z; As[akq+3][am] = av.w;
#pragma unroll
    for (int bnd = 0; bnd < 3; ++bnd) {
      Bs[bnd][bkq+0][bn_n] = bv[bnd].x; Bs[bnd][bkq+1][bn_n] = bv[bnd].y;
      Bs[bnd][bkq+2][bn_n] = bv[bnd].z; Bs[bnd][bkq+3][bn_n] = bv[bnd].w;
    }
    __syncthreads();
#pragma unroll
    for (int kk = 0; kk < BK; ++kk) {
      float4 a4 = *reinterpret_cast<const float4*>(&As[kk][ty*4]);
      float a[4] = {a4.x,a4.y,a4.z,a4.w};
      {
        float4 b4 = *reinterpret_cast<const float4*>(&Bs[0][kk][tx*4]);
        float b[4] = {b4.x,b4.y,b4.z,b4.w};
#pragma unroll
        for (int i = 0; i < 4; ++i)
#pragma unroll
          for (int j = 0; j < 4; ++j) acc[0][i][j] += a[i]*b[j];
      }
      {
        float4 b4 = *reinterpret_cast<const float4*>(&Bs[1][kk][tx*4]);
        float b[4] = {b4.x,b4.y,b4.z,b4.w};
#pragma unroll
        for (int i = 0; i < 4; ++i)
#pragma unroll
          for (int j = 0; j < 4; ++j) acc[1][i][j] += a[i]*b[j];
      }
      {
        float4 b4 = *reinterpret_cast<const float4*>(&Bs[2][kk][tx*4]);
        float b[4] = {b4.x,b4.y,b4.z,b4.w};
#pragma unroll
        for (int i = 0; i < 4; ++i)
#pragma unroll
          for (int j = 0; j < 4; ++j) acc[3][i][j] += a[i]*b[j];
      }
    }
  }
  // ---- epilogue: gates ----
  float tr[4];
#pragma unroll
  for (int i = 0; i < 4; ++i) tr[i] = tension[row0 + ty*4 + i];
#pragma unroll
  for (int j = 0; j < 4; ++j) {
    int jj = j0 + tx*4 + j;
    float wr = ld1(Wih, wihL + (size_t)(       jj)*513 + 512, f32);
    float wz = ld1(Wih, wihL + (size_t)(1024 + jj)*513 + 512, f32);
    float wn = ld1(Wih, wihL + (size_t)(2048 + jj)*513 + 512, f32);
    float bir  = ld1(bih, l*G3 + jj, f32),        bhr = ld1(bhh, l*G3 + jj, f32);
    float biz  = ld1(bih, l*G3 + 1024 + jj, f32), bhz = ld1(bhh, l*G3 + 1024 + jj, f32);
    float bin_ = ld1(bih, l*G3 + 2048 + jj, f32), bhn = ld1(bhh, l*G3 + 2048 + jj, f32);
#pragma unroll
    for (int i = 0; i < 4; ++i) {
      int r = row0 + ty*4 + i;
      float rg = sigm(acc[0][i][j] + tr[i]*wr + bir + bhr);
      float zg = sigm(acc[1][i][j] + tr[i]*wz + biz + bhz);
      float ng = tanhf(acc[2][i][j] + tr[i]*wn + bin_ + rg*(acc[3][i][j] + bhn));
      float hv = ld1(H, (size_t)r*HID + jj, f32);
      st1(outv, 513 + (size_t)r*HID + jj, (1.0f - zg)*ng + zg*hv, f32);
    }
  }
}

// level means: lm[l, j] = mean_c new_h[l, c, j]   (new_h lives in d_out hh region)
__global__ void k_lm(const void* __restrict__ outv, const int* __restrict__ dflag,
                     float* __restrict__ lm) {
  const bool f32 = dflag[0] != 0;
  int l = blockIdx.y;
  int j = blockIdx.x*256 + threadIdx.x;
  size_t base = 513 + (size_t)l*CPL*HID + j;
  float s = 0.0f;
  for (int c = 0; c < CPL; ++c) s += ld1(outv, base + (size_t)c*HID, f32);
  lm[l*HID + j] = s * (1.0f/1024.0f);
}

// pz[lv] = relu(lm[lv+1] @ pred_W1[lv] + b1)
__global__ void k_pz(const float* __restrict__ lm, const void* __restrict__ pW1,
                     const void* __restrict__ pb1, const int* __restrict__ dflag,
                     float* __restrict__ pz) {
  const bool f32 = dflag[0] != 0;
  int lv = blockIdx.y;
  int m = blockIdx.x*256 + threadIdx.x;
  float acc = ld1(pb1, lv*HID + m, f32);
  size_t wb = (size_t)lv*HID*HID + m;
  const float* lmp = lm + (lv + 1)*HID;
  for (int i = 0; i < HID; ++i) acc += lmp[i] * ld1(pW1, wb + (size_t)i*HID, f32);
  pz[lv*HID + m] = acc > 0.0f ? acc : 0.0f;
}

// pe[lv] = (pz[lv] @ pred_W2[lv] + b2 - lm[lv]) * 0.05
__global__ void k_pe(const float* __restrict__ pz, const void* __restrict__ pW2,
                     const void* __restrict__ pb2, const float* __restrict__ lm,
                     const int* __restrict__ dflag, float* __restrict__ pe) {
  const bool f32 = dflag[0] != 0;
  int lv = blockIdx.y;
  int o = blockIdx.x*256 + threadIdx.x;
  float acc = ld1(pb2, lv*HID + o, f32);
  size_t wb = (size_t)lv*HID*HID + o;
  const float* pzp = pz + lv*HID;
  for (int m = 0; m < HID; ++m) acc += pzp[m] * ld1(pW2, wb + (size_t)m*HID, f32);
  pe[lv*HID + o] = (acc - lm[lv*HID + o]) * 0.05f;
}

// addc[l,j] = 0.2775*lm + delta;  gop[j] = mean_l(lm + delta)
__global__ void k_addc_gop(const float* __restrict__ lm, const float* __restrict__ pe,
                           float* __restrict__ addc, float* __restrict__ gop) {
  int j = blockIdx.x*256 + threadIdx.x;
  float pe0 = pe[j], pe1 = pe[1024 + j], pe2 = pe[2048 + j];
  float d0 = pe0, d1 = pe1 - 0.5f*pe0, d2 = pe2 - 0.5f*pe1, d3 = -0.5f*pe2;
  float l0 = lm[j], l1 = lm[1024 + j], l2 = lm[2048 + j], l3 = lm[3072 + j];
  addc[j]        = 0.2775f*l0 + d0;
  addc[1024 + j] = 0.2775f*l1 + d1;
  addc[2048 + j] = 0.2775f*l2 + d2;
  addc[3072 + j] = 0.2775f*l3 + d3;
  gop[j] = 0.25f*((l0 + d0) + (l1 + d1) + (l2 + d2) + (l3 + d3));
}

// combined = lm_flat @ pei_W + pei_b; also writes avg_tension
__global__ void k_combined(const float* __restrict__ lm, const void* __restrict__ peiW,
                           const void* __restrict__ peib, const float* __restrict__ tsum,
                           const int* __restrict__ dflag, void* __restrict__ outv) {
  const bool f32 = dflag[0] != 0;
  int o = blockIdx.x*256 + threadIdx.x;
  float acc = ld1(peib, o, f32);
  for (int i = 0; i < ROWS; ++i) acc += lm[i] * ld1(peiW, (size_t)i*OUTD + o, f32);
  st1(outv, o, acc, f32);
  if (o == 0) st1(outv, 512, tsum[0] * (1.0f/(4096.0f*512.0f)), f32);
}

// hh = 0.7225*new_h + addc[l];  debate mix for c < 256.  In-place on d_out hh region.
__global__ void k_hh(void* __restrict__ outv, const float* __restrict__ addc,
                     const float* __restrict__ gop, const int* __restrict__ step,
                     const int* __restrict__ dflag) {
  const bool f32 = dflag[0] != 0;
  int row = blockIdx.x, t = threadIdx.x;
  int l = row >> 10, c = row & 1023;
  bool debate = (step[0] > 5) && (c < 256);
  size_t base = 513 + (size_t)row*HID;
#pragma unroll
  for (int k = 0; k < 4; ++k) {
    int j = t + k*256;
    float v = 0.7225f * ld1(outv, base + j, f32) + addc[l*HID + j];
    if (debate) v = 0.85f*v + 0.15f*gop[j];
    st1(outv, base + j, v, f32);
  }
}

extern "C" void kernel_launch(void* const* d_in, const int* in_sizes, int n_in,
                              void* d_out, int out_size, void* d_ws, size_t ws_size,
                              hipStream_t stream) {
  (void)in_sizes; (void)n_in; (void)out_size; (void)ws_size;
  const void* x    = d_in[0];
  const void* hid  = d_in[1];
  const void* eaW1 = d_in[2];
  const void* eab1 = d_in[3];
  const void* eaW2 = d_in[4];
  const void* eab2 = d_in[5];
  const void* egW1 = d_in[6];
  const void* egb1 = d_in[7];
  const void* egW2 = d_in[8];
  const void* egb2 = d_in[9];
  const void* gWih = d_in[10];
  const void* gWhh = d_in[11];
  const void* gbih = d_in[12];
  const void* gbhh = d_in[13];
  const void* pW1  = d_in[14];
  const void* pb1  = d_in[15];
  const void* pW2  = d_in[16];
  const void* pb2  = d_in[17];
  const void* peiW = d_in[18];
  const void* peib = d_in[19];
  const int*  step = (const int*)d_in[20];

  // workspace: fp32 scratch + Zb (4096x256 bf16) + OUTm (4096x512 bf16), ~6.2 MB
  float* wsf     = (float*)d_ws;
  float* tsum    = wsf;                  // 64
  int*   dflag   = (int*)(wsf + 64);     // 1 (+pad to 64)
  float* tension = wsf + 128;            // 4096
  float* base    = wsf + 4224;           // 1024
  float* lm      = wsf + 5248;           // 4096
  float* pe      = wsf + 9344;           // 3072
  float* pz      = wsf + 12416;          // 3072
  float* addc    = wsf + 15488;          // 4096
  float* gop     = wsf + 19584;          // 1024
  u16* Zb   = (u16*)(wsf + 20608);       // 4096x256
  u16* OUTm = Zb + (size_t)1048576;      // 4096x512

  k_detect  <<<dim3(1),      dim3(256), 0, stream>>>(x, dflag, tsum);
  k_base    <<<dim3(4,2),    dim3(128), 0, stream>>>(x, eaW1, egW1, eab1, egb1, dflag, base);
  k_z       <<<dim3(64,4),   dim3(256), 0, stream>>>(hid, eaW1, egW1, base, dflag, Zb);
  k_out     <<<dim3(64,8),   dim3(256), 0, stream>>>(Zb, eaW2, egW2, eab2, egb2, dflag, OUTm);
  k_tension <<<dim3(4096),   dim3(256), 0, stream>>>(OUTm, tension, tsum);
  k_gru     <<<dim3(64,16),  dim3(256), 0, stream>>>(OUTm, hid, gWih, gWhh, gbih, gbhh,
                                                     tension, dflag, d_out);
  k_lm      <<<dim3(4,4),    dim3(256), 0, stream>>>(d_out, dflag, lm);
  k_pz      <<<dim3(4,3),    dim3(256), 0, stream>>>(lm, pW1, pb1, dflag, pz);
  k_pe      <<<dim3(4,3),    dim3(256), 0, stream>>>(pz, pW2, pb2, lm, dflag, pe);
  k_addc_gop<<<dim3(4),      dim3(256), 0, stream>>>(lm, pe, addc, gop);
  k_combined<<<dim3(2),      dim3(256), 0, stream>>>(lm, peiW, peib, tsum, dflag, d_out);
  k_hh      <<<dim3(4096),   dim3(256), 0, stream>>>(d_out, addc, gop, step, dflag);
}

// Round 4
// 683.916 us; speedup vs baseline: 2.9397x; 2.9397x over previous
//
#include <hip/hip_runtime.h>
#include <math.h>

// Problem constants
#define L4   4
#define CPL  1024
#define HID  1024
#define IND  512
#define MLPD 128
#define OUTD 512
#define G3   3072
#define ROWS 4096   // L4*CPL
#define KP   544    // padded gi K: 512 OUT + 1 tension + 31 zeros

typedef unsigned short u16;
typedef u16   u16x8  __attribute__((ext_vector_type(8)));
typedef short bf16x8 __attribute__((ext_vector_type(8)));
typedef float f32x4  __attribute__((ext_vector_type(4)));

__device__ __forceinline__ float b2f(u16 u) {
  return __uint_as_float(((unsigned int)u) << 16);
}
__device__ __forceinline__ u16 f2b(float f) {   // round-to-nearest-even
  unsigned int x = __float_as_uint(f);
  x += 0x7fffu + ((x >> 16) & 1u);
  return (u16)(x >> 16);
}
__device__ __forceinline__ float sigm(float v) { return 1.0f/(1.0f + expf(-v)); }

// ---- dual-dtype access helpers: f32 flag selects float32 vs bf16 layout ----
struct F4 { float x, y, z, w; };
__device__ __forceinline__ F4 ld4(const void* p, size_t i, bool f32) {
  F4 r;
  if (f32) {
    float4 v = *reinterpret_cast<const float4*>((const float*)p + i);
    r.x = v.x; r.y = v.y; r.z = v.z; r.w = v.w;
  } else {
    ushort4 v = *reinterpret_cast<const ushort4*>((const u16*)p + i);
    r.x = b2f(v.x); r.y = b2f(v.y); r.z = b2f(v.z); r.w = b2f(v.w);
  }
  return r;
}
__device__ __forceinline__ float ld1(const void* p, size_t i, bool f32) {
  return f32 ? ((const float*)p)[i] : b2f(((const u16*)p)[i]);
}
__device__ __forceinline__ void st1(void* p, size_t i, float v, bool f32) {
  if (f32) ((float*)p)[i] = v; else ((u16*)p)[i] = f2b(v);
}
// load 8 elems -> bf16x8 bits (converting if fp32). i must be multiple of 8.
__device__ __forceinline__ u16x8 ldc8(const void* p, size_t i, bool f32) {
  u16x8 r;
  if (f32) {
    const float* q = (const float*)p + i;
    float4 v0 = *reinterpret_cast<const float4*>(q);
    float4 v1 = *reinterpret_cast<const float4*>(q + 4);
    r[0]=f2b(v0.x); r[1]=f2b(v0.y); r[2]=f2b(v0.z); r[3]=f2b(v0.w);
    r[4]=f2b(v1.x); r[5]=f2b(v1.y); r[6]=f2b(v1.z); r[7]=f2b(v1.w);
  } else {
    r = *reinterpret_cast<const u16x8*>((const u16*)p + i);
  }
  return r;
}

// ---------------- dtype detector ----------------
__global__ void k_detect(const void* __restrict__ x, int* __restrict__ flag) {
  int t = threadIdx.x;   // 256
  const u16* xu = (const u16*)x;
  unsigned u = xu[2*t];
  int e = (u >> 7) & 0xFF;
  int good = (e >= 96 && e <= 134) ? 1 : 0;
  __shared__ int cnt[256];
  cnt[t] = good;
  __syncthreads();
  for (int s = 128; s > 0; s >>= 1) { if (t < s) cnt[t] += cnt[t+s]; __syncthreads(); }
  if (t == 0) flag[0] = (cnt[0] < 200) ? 1 : 0;   // 1 = float32, 0 = bf16
}

// ---------------- prep: zero accumulators + bias sums ----------------
// zero region: wsf[0 .. 12288) ; bias arrays bs_r/bs_z/bn_i/bn_h [4][1024] fp32
__global__ void k_prep(float* __restrict__ zf, const void* __restrict__ bih,
                       const void* __restrict__ bhh, const int* __restrict__ dflag,
                       float* __restrict__ bs_r, float* __restrict__ bs_z,
                       float* __restrict__ bn_i, float* __restrict__ bn_h) {
  const bool f32 = dflag[0] != 0;
  int b = blockIdx.x, t = threadIdx.x;
  if (b < 16) {
    int idx = b*256 + t;          // [0,4096)
    int l = idx >> 10, j = idx & 1023;
    bs_r[idx] = ld1(bih, l*G3 + j, f32)        + ld1(bhh, l*G3 + j, f32);
    bs_z[idx] = ld1(bih, l*G3 + 1024 + j, f32) + ld1(bhh, l*G3 + 1024 + j, f32);
    bn_i[idx] = ld1(bih, l*G3 + 2048 + j, f32);
    bn_h[idx] = ld1(bhh, l*G3 + 2048 + j, f32);
  } else {
    int idx = (b-16)*256 + t;     // [0,12288)
    zf[idx] = 0.0f;
  }
}

// ---------------- repack Wih -> bf16 [4][3072][544] (col 512 = tension wt, rest 0) ----
__global__ void k_prep_wih(const void* __restrict__ Wih, const int* __restrict__ dflag,
                           u16* __restrict__ WihP) {
  const bool f32 = dflag[0] != 0;
  int row = blockIdx.x;            // 0..12287 == l*3072+g
  int t = threadIdx.x;
  size_t src = (size_t)row * 513;
  size_t dst = (size_t)row * KP;
  WihP[dst + t]       = f2b(ld1(Wih, src + t, f32));
  WihP[dst + 256 + t] = f2b(ld1(Wih, src + 256 + t, f32));
  if (t < 32) {
    float v = (t == 0) ? ld1(Wih, src + 512, f32) : 0.0f;
    WihP[dst + 512 + t] = f2b(v);
  }
}

// ---------------- base accumulation (x part of encoder layer 1) ----------------
// baseacc[path*512 + l*128 + m] += sum_{i in chunk} x[i]*W1[l,i,m]
__global__ void k_base_acc(const void* __restrict__ x, const void* __restrict__ eaW1,
                           const void* __restrict__ egW1, const int* __restrict__ dflag,
                           float* __restrict__ baseacc) {
  const bool f32 = dflag[0] != 0;
  int l = blockIdx.x, path = blockIdx.y, kc = blockIdx.z, m = threadIdx.x; // 128 thr
  const void* W1 = path ? egW1 : eaW1;
  float acc = 0.0f;
  int i0 = kc*128;
  for (int i = i0; i < i0 + 128; ++i)
    acc += ld1(x, i, f32) * ld1(W1, ((size_t)l*1536 + i)*MLPD + m, f32);
  atomicAdd(&baseacc[path*512 + l*MLPD + m], acc);
}

// ---------------- tiled VALU GEMMs for encoder (small) ----------------
#define BM 64
#define BN 64
#define BK 16

// Z = relu(base + b1 + H @ W1[512:,:])   output Z bf16 [4096, 256] (a | g)
__global__ __launch_bounds__(256) void k_z(
    const void* __restrict__ A, const void* __restrict__ eaW1, const void* __restrict__ egW1,
    const void* __restrict__ eab1, const void* __restrict__ egb1,
    const float* __restrict__ baseacc, const int* __restrict__ dflag, u16* __restrict__ Z) {
  const bool f32 = dflag[0] != 0;
  __shared__ float As[BK][BM];
  __shared__ float Bs[BK][BN];
  int t = threadIdx.x;
  int row0 = blockIdx.x * BM;
  int n0   = blockIdx.y * BN;          // 0,64,128,192
  int l    = row0 >> 10;
  int path = n0 >> 7;
  int mc0  = n0 & 127;
  const void* B  = path ? egW1 : eaW1;
  const void* b1 = path ? egb1 : eab1;
  size_t boff = (size_t)l*1536*MLPD + (size_t)IND*MLPD + mc0;
  int tx = t & 15, ty = t >> 4;
  int am = t >> 2, akq = (t & 3) * 4;
  int bk = t >> 4, bn = (t & 15) * 4;

  float acc[4][4];
  {
    float bv[4];
#pragma unroll
    for (int j = 0; j < 4; ++j) {
      int m = mc0 + tx*4 + j;
      bv[j] = baseacc[path*512 + l*MLPD + m] + ld1(b1, l*MLPD + m, f32);
    }
#pragma unroll
    for (int i = 0; i < 4; ++i)
#pragma unroll
      for (int j = 0; j < 4; ++j) acc[i][j] = bv[j];
  }
  for (int k0 = 0; k0 < HID; k0 += BK) {
    F4 av = ld4(A, (size_t)(row0 + am)*HID + k0 + akq, f32);
    F4 bv = ld4(B, boff + (size_t)(k0 + bk)*MLPD + bn, f32);
    __syncthreads();
    As[akq+0][am] = av.x; As[akq+1][am] = av.y;
    As[akq+2][am] = av.z; As[akq+3][am] = av.w;
    Bs[bk][bn+0] = bv.x; Bs[bk][bn+1] = bv.y;
    Bs[bk][bn+2] = bv.z; Bs[bk][bn+3] = bv.w;
    __syncthreads();
#pragma unroll
    for (int kk = 0; kk < BK; ++kk) {
      float4 a4 = *reinterpret_cast<const float4*>(&As[kk][ty*4]);
      float4 b4 = *reinterpret_cast<const float4*>(&Bs[kk][tx*4]);
      float a[4] = {a4.x,a4.y,a4.z,a4.w};
      float b[4] = {b4.x,b4.y,b4.z,b4.w};
#pragma unroll
      for (int i = 0; i < 4; ++i)
#pragma unroll
        for (int j = 0; j < 4; ++j) acc[i][j] += a[i]*b[j];
    }
  }
#pragma unroll
  for (int i = 0; i < 4; ++i) {
    int r = row0 + ty*4 + i;
#pragma unroll
    for (int j = 0; j < 4; ++j) {
      float v = acc[i][j]; v = v > 0.0f ? v : 0.0f;
      Z[(size_t)r*256 + n0 + tx*4 + j] = f2b(v);
    }
  }
}

// OUT = Za@W2a - Zg@W2g + (b2a-b2g)  -> OUTT [4096,544] cols 0..511
__global__ __launch_bounds__(256) void k_out(
    const u16* __restrict__ Zb, const void* __restrict__ eaW2, const void* __restrict__ egW2,
    const void* __restrict__ eab2, const void* __restrict__ egb2,
    const int* __restrict__ dflag, u16* __restrict__ OUTT) {
  const bool f32 = dflag[0] != 0;
  __shared__ float As[BK][BM];
  __shared__ float Bs[BK][BN];
  int t = threadIdx.x;
  int row0 = blockIdx.x * BM;
  int n0   = blockIdx.y * BN;          // 0..448
  int l    = row0 >> 10;
  const u16* Ab = Zb + (size_t)row0 * 256;
  int tx = t & 15, ty = t >> 4;
  int am = t >> 2, akq = (t & 3) * 4;
  int bk = t >> 4, bn = (t & 15) * 4;

  float acc[4][4];
#pragma unroll
  for (int j = 0; j < 4; ++j) {
    int o = n0 + tx*4 + j;
    float bd = ld1(eab2, l*OUTD + o, f32) - ld1(egb2, l*OUTD + o, f32);
#pragma unroll
    for (int i = 0; i < 4; ++i) acc[i][j] = bd;
  }

  for (int ph = 0; ph < 2; ++ph) {
    const void* B = ph ? egW2 : eaW2;
    size_t boff = (size_t)l*MLPD*OUTD + n0;
    float sgn = ph ? -1.0f : 1.0f;
    for (int k0 = 0; k0 < MLPD; k0 += BK) {
      ushort4 av = *reinterpret_cast<const ushort4*>(Ab + (size_t)am*256 + ph*128 + k0 + akq);
      F4 bv = ld4(B, boff + (size_t)(k0 + bk)*OUTD + bn, f32);
      __syncthreads();
      As[akq+0][am] = b2f(av.x); As[akq+1][am] = b2f(av.y);
      As[akq+2][am] = b2f(av.z); As[akq+3][am] = b2f(av.w);
      Bs[bk][bn+0] = sgn*bv.x; Bs[bk][bn+1] = sgn*bv.y;
      Bs[bk][bn+2] = sgn*bv.z; Bs[bk][bn+3] = sgn*bv.w;
      __syncthreads();
#pragma unroll
      for (int kk = 0; kk < BK; ++kk) {
        float4 a4 = *reinterpret_cast<const float4*>(&As[kk][ty*4]);
        float4 b4 = *reinterpret_cast<const float4*>(&Bs[kk][tx*4]);
        float a[4] = {a4.x,a4.y,a4.z,a4.w};
        float b[4] = {b4.x,b4.y,b4.z,b4.w};
#pragma unroll
        for (int i = 0; i < 4; ++i)
#pragma unroll
          for (int j = 0; j < 4; ++j) acc[i][j] += a[i]*b[j];
      }
    }
  }
#pragma unroll
  for (int i = 0; i < 4; ++i) {
    int r = row0 + ty*4 + i;
#pragma unroll
    for (int j = 0; j < 4; ++j)
      OUTT[(size_t)r*KP + n0 + tx*4 + j] = f2b(acc[i][j]);
  }
}

// tension -> OUTT col 512 (bf16); zero pad cols 513..543; tsum += sumsq(row)
__global__ void k_tension(u16* __restrict__ OUTT, float* __restrict__ tsum) {
  int row = blockIdx.x, t = threadIdx.x;
  u16* p = OUTT + (size_t)row*KP;
  float v0 = b2f(p[t]), v1 = b2f(p[t+256]);
  float s = v0*v0 + v1*v1;
#pragma unroll
  for (int off = 32; off > 0; off >>= 1) s += __shfl_down(s, off, 64);
  __shared__ float red[4];
  if ((t & 63) == 0) red[t >> 6] = s;
  __syncthreads();
  if (t == 0) {
    float tot = red[0] + red[1] + red[2] + red[3];
    p[512] = f2b(tot * (1.0f/512.0f));
    atomicAdd(tsum, tot);
  }
  if (t < 31) p[513 + t] = 0;   // zero pad (ws is poisoned each launch)
}

// ---------------- fused MFMA GRU ----------------
// gi = OUTT[4096,544] @ WihP^T (tension folded in); gh = H @ Whh^T; gates -> new_h
#define LPAD 40
__global__ __launch_bounds__(256) void k_gru_mfma(
    const u16* __restrict__ OUTT, const void* __restrict__ H,
    const u16* __restrict__ WihP, const void* __restrict__ Whh,
    const float* __restrict__ bs_r, const float* __restrict__ bs_z,
    const float* __restrict__ bn_i, const float* __restrict__ bn_h,
    const int* __restrict__ dflag, void* __restrict__ outv) {
  const bool f32 = dflag[0] != 0;
  __shared__ u16 sA[64*LPAD];
  __shared__ u16 sB[3][64*LPAD];
  int t = threadIdx.x;
  int row0 = blockIdx.x * 64;        // cell rows
  int j0   = blockIdx.y * 64;        // hidden unit j
  int l    = row0 >> 10;
  int wid = t >> 6, lane = t & 63;
  int waveM = wid >> 1, waveN = wid & 1;
  int quad = lane >> 4, lcol = lane & 15;
  int arow = t >> 2, kq = (t & 3) * 8;   // staging coords: 8 elems/thread

  f32x4 acc[4][2][2];   // bands r,z,i_n,h_n
  const f32x4 zz = {0.0f, 0.0f, 0.0f, 0.0f};
#pragma unroll
  for (int b = 0; b < 4; ++b)
#pragma unroll
    for (int i = 0; i < 2; ++i)
#pragma unroll
      for (int j = 0; j < 2; ++j) acc[b][i][j] = zz;

  // ---- GEMM1: gi over K=544 (bf16 staged ws, includes tension col) ----
  {
    const u16* Ab = OUTT + (size_t)row0 * KP;
    const u16* Bb = WihP + (size_t)l * G3 * KP + (size_t)j0 * KP;
    for (int k0 = 0; k0 < KP; k0 += 32) {
      u16x8 av = *reinterpret_cast<const u16x8*>(Ab + (size_t)arow*KP + k0 + kq);
      u16x8 bv[3];
#pragma unroll
      for (int b = 0; b < 3; ++b)
        bv[b] = *reinterpret_cast<const u16x8*>(Bb + ((size_t)b*1024 + arow)*KP + k0 + kq);
      __syncthreads();
      *reinterpret_cast<u16x8*>(&sA[arow*LPAD + kq]) = av;
#pragma unroll
      for (int b = 0; b < 3; ++b)
        *reinterpret_cast<u16x8*>(&sB[b][arow*LPAD + kq]) = bv[b];
      __syncthreads();
      bf16x8 af[2];
#pragma unroll
      for (int i = 0; i < 2; ++i)
        af[i] = *reinterpret_cast<const bf16x8*>(&sA[(waveM*32 + i*16 + lcol)*LPAD + quad*8]);
#pragma unroll
      for (int b = 0; b < 3; ++b)
#pragma unroll
        for (int j = 0; j < 2; ++j) {
          bf16x8 bf = *reinterpret_cast<const bf16x8*>(
              &sB[b][(waveN*32 + j*16 + lcol)*LPAD + quad*8]);
#pragma unroll
          for (int i = 0; i < 2; ++i)
            acc[b][i][j] = __builtin_amdgcn_mfma_f32_16x16x32_bf16(af[i], bf, acc[b][i][j], 0, 0, 0);
        }
    }
  }
  // ---- GEMM2: gh over K=1024 (dual-dtype converted on stage) ----
  {
    size_t hbase = (size_t)row0 * HID;
    size_t wbase = (size_t)l * G3 * HID + (size_t)j0 * HID;
    for (int k0 = 0; k0 < HID; k0 += 32) {
      u16x8 av = ldc8(H, hbase + (size_t)arow*HID + k0 + kq, f32);
      u16x8 bv[3];
#pragma unroll
      for (int b = 0; b < 3; ++b)
        bv[b] = ldc8(Whh, wbase + ((size_t)b*1024 + arow)*HID + k0 + kq, f32);
      __syncthreads();
      *reinterpret_cast<u16x8*>(&sA[arow*LPAD + kq]) = av;
#pragma unroll
      for (int b = 0; b < 3; ++b)
        *reinterpret_cast<u16x8*>(&sB[b][arow*LPAD + kq]) = bv[b];
      __syncthreads();
      bf16x8 af[2];
#pragma unroll
      for (int i = 0; i < 2; ++i)
        af[i] = *reinterpret_cast<const bf16x8*>(&sA[(waveM*32 + i*16 + lcol)*LPAD + quad*8]);
#pragma unroll
      for (int b = 0; b < 3; ++b) {
        int ai = (b < 2) ? b : 3;   // n band of gh -> acc[3]
#pragma unroll
        for (int j = 0; j < 2; ++j) {
          bf16x8 bf = *reinterpret_cast<const bf16x8*>(
              &sB[b][(waveN*32 + j*16 + lcol)*LPAD + quad*8]);
#pragma unroll
          for (int i = 0; i < 2; ++i)
            acc[ai][i][j] = __builtin_amdgcn_mfma_f32_16x16x32_bf16(af[i], bf, acc[ai][i][j], 0, 0, 0);
        }
      }
    }
  }
  // ---- epilogue: gates -> new_h into d_out hh region ----
#pragma unroll
  for (int i = 0; i < 2; ++i)
#pragma unroll
    for (int j = 0; j < 2; ++j) {
      int jj = j0 + waveN*32 + j*16 + lcol;
      float br = bs_r[l*HID + jj], bz = bs_z[l*HID + jj];
      float bi = bn_i[l*HID + jj], bh = bn_h[l*HID + jj];
#pragma unroll
      for (int g = 0; g < 4; ++g) {
        int r = row0 + waveM*32 + i*16 + quad*4 + g;
        float rg = sigm(acc[0][i][j][g] + br);
        float zg = sigm(acc[1][i][j][g] + bz);
        float ng = tanhf(acc[2][i][j][g] + bi + rg*(acc[3][i][j][g] + bh));
        float hv = ld1(H, (size_t)r*HID + jj, f32);
        st1(outv, 513 + (size_t)r*HID + jj, (1.0f - zg)*ng + zg*hv, f32);
      }
    }
}

// ---------------- level means (split-C atomics) ----------------
__global__ void k_lm_acc(const void* __restrict__ outv, const int* __restrict__ dflag,
                         float* __restrict__ lm) {
  const bool f32 = dflag[0] != 0;
  int l = blockIdx.x, cc = blockIdx.y, t = threadIdx.x;
  float s0=0.f, s1=0.f, s2=0.f, s3=0.f;
  for (int c = cc*64; c < cc*64 + 64; ++c) {
    size_t base = 513 + (size_t)(l*CPL + c)*HID;
    s0 += ld1(outv, base + t,       f32);
    s1 += ld1(outv, base + 256 + t, f32);
    s2 += ld1(outv, base + 512 + t, f32);
    s3 += ld1(outv, base + 768 + t, f32);
  }
  atomicAdd(&lm[l*HID + t],       s0);
  atomicAdd(&lm[l*HID + 256 + t], s1);
  atomicAdd(&lm[l*HID + 512 + t], s2);
  atomicAdd(&lm[l*HID + 768 + t], s3);
}
__global__ void k_lmfin(float* __restrict__ lm) {
  int idx = blockIdx.x*256 + threadIdx.x;
  lm[idx] *= (1.0f/1024.0f);
}

// ---------------- predictors (split-K atomics) ----------------
__global__ void k_pz_acc(const float* __restrict__ lm, const void* __restrict__ pW1,
                         const int* __restrict__ dflag, float* __restrict__ pz) {
  const bool f32 = dflag[0] != 0;
  int lv = blockIdx.x, mb = blockIdx.y, kc = blockIdx.z;
  int m = mb*256 + threadIdx.x;
  float acc = 0.0f;
  int i0 = kc*128;
  const float* lmp = lm + (lv + 1)*HID;
  for (int i = i0; i < i0 + 128; ++i)
    acc += lmp[i] * ld1(pW1, ((size_t)lv*HID + i)*HID + m, f32);
  atomicAdd(&pz[lv*HID + m], acc);
}
__global__ void k_pzfin(float* __restrict__ pz, const void* __restrict__ pb1,
                        const int* __restrict__ dflag) {
  const bool f32 = dflag[0] != 0;
  int idx = blockIdx.x*256 + threadIdx.x;   // [0,3072)
  float v = pz[idx] + ld1(pb1, idx, f32);
  pz[idx] = v > 0.0f ? v : 0.0f;
}
__global__ void k_pe_acc(const float* __restrict__ pz, const void* __restrict__ pW2,
                         const int* __restrict__ dflag, float* __restrict__ pe) {
  const bool f32 = dflag[0] != 0;
  int lv = blockIdx.x, ob = blockIdx.y, kc = blockIdx.z;
  int o = ob*256 + threadIdx.x;
  float acc = 0.0f;
  int m0 = kc*128;
  const float* pzp = pz + lv*HID;
  for (int m = m0; m < m0 + 128; ++m)
    acc += pzp[m] * ld1(pW2, ((size_t)lv*HID + m)*HID + o, f32);
  atomicAdd(&pe[lv*HID + o], acc);
}
__global__ void k_pefin(float* __restrict__ pe, const void* __restrict__ pb2,
                        const float* __restrict__ lm, const int* __restrict__ dflag) {
  const bool f32 = dflag[0] != 0;
  int idx = blockIdx.x*256 + threadIdx.x;   // [0,3072)
  pe[idx] = (pe[idx] + ld1(pb2, idx, f32) - lm[idx]) * 0.05f;
}

// addc[l,j] = 0.2775*lm + delta;  gop[j] = mean_l(lm + delta)
__global__ void k_addc_gop(const float* __restrict__ lm, const float* __restrict__ pe,
                           float* __restrict__ addc, float* __restrict__ gop) {
  int j = blockIdx.x*256 + threadIdx.x;
  float pe0 = pe[j], pe1 = pe[1024 + j], pe2 = pe[2048 + j];
  float d0 = pe0, d1 = pe1 - 0.5f*pe0, d2 = pe2 - 0.5f*pe1, d3 = -0.5f*pe2;
  float l0 = lm[j], l1 = lm[1024 + j], l2 = lm[2048 + j], l3 = lm[3072 + j];
  addc[j]        = 0.2775f*l0 + d0;
  addc[1024 + j] = 0.2775f*l1 + d1;
  addc[2048 + j] = 0.2775f*l2 + d2;
  addc[3072 + j] = 0.2775f*l3 + d3;
  gop[j] = 0.25f*((l0 + d0) + (l1 + d1) + (l2 + d2) + (l3 + d3));
}

// combined = lm_flat @ pei_W (split-K atomics)
__global__ void k_comb_acc(const float* __restrict__ lm, const void* __restrict__ peiW,
                           const int* __restrict__ dflag, float* __restrict__ comb) {
  const bool f32 = dflag[0] != 0;
  int ob = blockIdx.x, kc = blockIdx.y;
  int o = ob*256 + threadIdx.x;
  float acc = 0.0f;
  int i0 = kc*256;
  for (int i = i0; i < i0 + 256; ++i)
    acc += lm[i] * ld1(peiW, (size_t)i*OUTD + o, f32);
  atomicAdd(&comb[o], acc);
}
__global__ void k_fin(const float* __restrict__ comb, const void* __restrict__ peib,
                      const float* __restrict__ tsum, const int* __restrict__ dflag,
                      void* __restrict__ outv) {
  const bool f32 = dflag[0] != 0;
  int o = blockIdx.x*256 + threadIdx.x;
  st1(outv, o, comb[o] + ld1(peib, o, f32), f32);
  if (o == 0) st1(outv, 512, tsum[0] * (1.0f/(4096.0f*512.0f)), f32);
}

// hh = 0.7225*new_h + addc[l]; debate mix for c < 256.  In-place on d_out hh region.
__global__ void k_hh(void* __restrict__ outv, const float* __restrict__ addc,
                     const float* __restrict__ gop, const int* __restrict__ step,
                     const int* __restrict__ dflag) {
  const bool f32 = dflag[0] != 0;
  int row = blockIdx.x, t = threadIdx.x;
  int l = row >> 10, c = row & 1023;
  bool debate = (step[0] > 5) && (c < 256);
  size_t base = 513 + (size_t)row*HID;
#pragma unroll
  for (int k = 0; k < 4; ++k) {
    int j = t + k*256;
    float v = 0.7225f * ld1(outv, base + j, f32) + addc[l*HID + j];
    if (debate) v = 0.85f*v + 0.15f*gop[j];
    st1(outv, base + j, v, f32);
  }
}

extern "C" void kernel_launch(void* const* d_in, const int* in_sizes, int n_in,
                              void* d_out, int out_size, void* d_ws, size_t ws_size,
                              hipStream_t stream) {
  (void)in_sizes; (void)n_in; (void)out_size; (void)ws_size;
  const void* x    = d_in[0];
  const void* hid  = d_in[1];
  const void* eaW1 = d_in[2];
  const void* eab1 = d_in[3];
  const void* eaW2 = d_in[4];
  const void* eab2 = d_in[5];
  const void* egW1 = d_in[6];
  const void* egb1 = d_in[7];
  const void* egW2 = d_in[8];
  const void* egb2 = d_in[9];
  const void* gWih = d_in[10];
  const void* gWhh = d_in[11];
  const void* gbih = d_in[12];
  const void* gbhh = d_in[13];
  const void* pW1  = d_in[14];
  const void* pb1  = d_in[15];
  const void* pW2  = d_in[16];
  const void* pb2  = d_in[17];
  const void* peiW = d_in[18];
  const void* peib = d_in[19];
  const int*  step = (const int*)d_in[20];

  // ---- workspace layout (floats), ~20 MB total ----
  float* wsf = (float*)d_ws;
  // zero region [0, 12288):
  float* tsum    = wsf + 0;       // 64
  float* baseacc = wsf + 64;      // 1024
  float* lm      = wsf + 1088;    // 4096
  float* pz      = wsf + 5184;    // 3072
  float* pe      = wsf + 8256;    // 3072
  float* comb    = wsf + 11328;   // 512 (+pad to 12288)
  int*   dflag   = (int*)(wsf + 12288);  // 64
  float* bs_r    = wsf + 12352;   // 4096
  float* bs_z    = wsf + 16448;   // 4096
  float* bn_i    = wsf + 20544;   // 4096
  float* bn_h    = wsf + 24640;   // 4096
  float* addc    = wsf + 28736;   // 4096
  float* gop     = wsf + 32832;   // 1024
  u16* Zb   = (u16*)(wsf + 33856);        // 4096*256
  u16* OUTT = Zb + (size_t)4096*256;      // 4096*544
  u16* WihP = OUTT + (size_t)4096*KP;     // 12288*544

  u16* outv = (u16*)d_out; (void)outv;

  k_detect   <<<dim3(1),        dim3(256), 0, stream>>>(x, dflag);
  k_prep     <<<dim3(64),       dim3(256), 0, stream>>>(wsf, gbih, gbhh, dflag,
                                                        bs_r, bs_z, bn_i, bn_h);
  k_prep_wih <<<dim3(12288),    dim3(256), 0, stream>>>(gWih, dflag, WihP);
  k_base_acc <<<dim3(4,2,4),    dim3(128), 0, stream>>>(x, eaW1, egW1, dflag, baseacc);
  k_z        <<<dim3(64,4),     dim3(256), 0, stream>>>(hid, eaW1, egW1, eab1, egb1,
                                                        baseacc, dflag, Zb);
  k_out      <<<dim3(64,8),     dim3(256), 0, stream>>>(Zb, eaW2, egW2, eab2, egb2,
                                                        dflag, OUTT);
  k_tension  <<<dim3(4096),     dim3(256), 0, stream>>>(OUTT, tsum);
  k_gru_mfma <<<dim3(64,16),    dim3(256), 0, stream>>>(OUTT, hid, WihP, gWhh,
                                                        bs_r, bs_z, bn_i, bn_h,
                                                        dflag, d_out);
  k_lm_acc   <<<dim3(4,16),     dim3(256), 0, stream>>>(d_out, dflag, lm);
  k_lmfin    <<<dim3(16),       dim3(256), 0, stream>>>(lm);
  k_pz_acc   <<<dim3(3,4,8),    dim3(256), 0, stream>>>(lm, pW1, dflag, pz);
  k_pzfin    <<<dim3(12),       dim3(256), 0, stream>>>(pz, pb1, dflag);
  k_pe_acc   <<<dim3(3,4,8),    dim3(256), 0, stream>>>(pz, pW2, dflag, pe);
  k_pefin    <<<dim3(12),       dim3(256), 0, stream>>>(pe, pb2, lm, dflag);
  k_addc_gop <<<dim3(4),        dim3(256), 0, stream>>>(lm, pe, addc, gop);
  k_comb_acc <<<dim3(2,16),     dim3(256), 0, stream>>>(lm, peiW, dflag, comb);
  k_fin      <<<dim3(2),        dim3(256), 0, stream>>>(comb, peib, tsum, dflag, d_out);
  k_hh       <<<dim3(4096),     dim3(256), 0, stream>>>(d_out, addc, gop, step, dflag);
}

// Round 6
// 668.788 us; speedup vs baseline: 3.0062x; 1.0226x over previous
//
#include <hip/hip_runtime.h>
#include <math.h>

// Problem constants
#define L4   4
#define CPL  1024
#define HID  1024
#define IND  512
#define MLPD 128
#define OUTD 512
#define G3   3072
#define ROWS 4096   // L4*CPL
#define KP   544    // padded gi K: 512 OUT + 1 tension + 31 zeros

typedef unsigned short u16;
typedef u16   u16x8  __attribute__((ext_vector_type(8)));
typedef short bf16x8 __attribute__((ext_vector_type(8)));
typedef float f32x4  __attribute__((ext_vector_type(4)));

__device__ __forceinline__ float b2f(u16 u) {
  return __uint_as_float(((unsigned int)u) << 16);
}
__device__ __forceinline__ u16 f2b(float f) {   // round-to-nearest-even
  unsigned int x = __float_as_uint(f);
  x += 0x7fffu + ((x >> 16) & 1u);
  return (u16)(x >> 16);
}
__device__ __forceinline__ float sigm(float v) { return 1.0f/(1.0f + expf(-v)); }

// ---- dual-dtype access helpers: f32 flag selects float32 vs bf16 layout ----
struct F4 { float x, y, z, w; };
__device__ __forceinline__ F4 ld4(const void* p, size_t i, bool f32) {
  F4 r;
  if (f32) {
    float4 v = *reinterpret_cast<const float4*>((const float*)p + i);
    r.x = v.x; r.y = v.y; r.z = v.z; r.w = v.w;
  } else {
    ushort4 v = *reinterpret_cast<const ushort4*>((const u16*)p + i);
    r.x = b2f(v.x); r.y = b2f(v.y); r.z = b2f(v.z); r.w = b2f(v.w);
  }
  return r;
}
__device__ __forceinline__ float ld1(const void* p, size_t i, bool f32) {
  return f32 ? ((const float*)p)[i] : b2f(((const u16*)p)[i]);
}
__device__ __forceinline__ void st1(void* p, size_t i, float v, bool f32) {
  if (f32) ((float*)p)[i] = v; else ((u16*)p)[i] = f2b(v);
}
// load 8 elems -> bf16 bits (converting if fp32). i must be multiple of 8.
__device__ __forceinline__ u16x8 ldc8(const void* p, size_t i, bool f32) {
  u16x8 r;
  if (f32) {
    const float* q = (const float*)p + i;
    float4 v0 = *reinterpret_cast<const float4*>(q);
    float4 v1 = *reinterpret_cast<const float4*>(q + 4);
    r[0]=f2b(v0.x); r[1]=f2b(v0.y); r[2]=f2b(v0.z); r[3]=f2b(v0.w);
    r[4]=f2b(v1.x); r[5]=f2b(v1.y); r[6]=f2b(v1.z); r[7]=f2b(v1.w);
  } else {
    r = *reinterpret_cast<const u16x8*>((const u16*)p + i);
  }
  return r;
}

// ---------------- dtype detector ----------------
__global__ void k_detect(const void* __restrict__ x, int* __restrict__ flag) {
  int t = threadIdx.x;   // 256
  const u16* xu = (const u16*)x;
  unsigned u = xu[2*t];
  int e = (u >> 7) & 0xFF;
  int good = (e >= 96 && e <= 134) ? 1 : 0;
  __shared__ int cnt[256];
  cnt[t] = good;
  __syncthreads();
  for (int s = 128; s > 0; s >>= 1) { if (t < s) cnt[t] += cnt[t+s]; __syncthreads(); }
  if (t == 0) flag[0] = (cnt[0] < 200) ? 1 : 0;   // 1 = float32, 0 = bf16
}

// ---------------- prep: zero accumulators + bias sums ----------------
__global__ void k_prep(float* __restrict__ zf, const void* __restrict__ bih,
                       const void* __restrict__ bhh, const int* __restrict__ dflag,
                       float* __restrict__ bs_r, float* __restrict__ bs_z,
                       float* __restrict__ bn_i, float* __restrict__ bn_h) {
  const bool f32 = dflag[0] != 0;
  int b = blockIdx.x, t = threadIdx.x;
  if (b < 16) {
    int idx = b*256 + t;          // [0,4096)
    int l = idx >> 10, j = idx & 1023;
    bs_r[idx] = ld1(bih, l*G3 + j, f32)        + ld1(bhh, l*G3 + j, f32);
    bs_z[idx] = ld1(bih, l*G3 + 1024 + j, f32) + ld1(bhh, l*G3 + 1024 + j, f32);
    bn_i[idx] = ld1(bih, l*G3 + 2048 + j, f32);
    bn_h[idx] = ld1(bhh, l*G3 + 2048 + j, f32);
  } else {
    int idx = (b-16)*256 + t;     // [0,12288)
    zf[idx] = 0.0f;
  }
}

// ---------------- repack Wih -> bf16 [4][3072][544] (col 512 = tension wt) ----
__global__ void k_prep_wih(const void* __restrict__ Wih, const int* __restrict__ dflag,
                           u16* __restrict__ WihP) {
  const bool f32 = dflag[0] != 0;
  int row = blockIdx.x;            // 0..12287 == l*3072+g
  int t = threadIdx.x;
  size_t src = (size_t)row * 513;
  size_t dst = (size_t)row * KP;
  WihP[dst + t]       = f2b(ld1(Wih, src + t, f32));
  WihP[dst + 256 + t] = f2b(ld1(Wih, src + 256 + t, f32));
  if (t < 32) {
    float v = (t == 0) ? ld1(Wih, src + 512, f32) : 0.0f;
    WihP[dst + 512 + t] = f2b(v);
  }
}

// ---------------- repack W1 hidden part -> bf16 transposed W1T[l][path*128+m][k] ----
// src: W1[l][512+k][m]  (k in [0,1024), m in [0,128))
__global__ void k_prep_w1t(const void* __restrict__ eaW1, const void* __restrict__ egW1,
                           const int* __restrict__ dflag, u16* __restrict__ W1T) {
  const bool f32 = dflag[0] != 0;
  __shared__ u16 sT[128*130];
  int l = blockIdx.x, path = blockIdx.y, kt = blockIdx.z;   // (4,2,8)
  int t = threadIdx.x;
  const void* W1 = path ? egW1 : eaW1;
  // read 128 k-rows x 128 m (coalesced over m), store transposed in LDS
  for (int rr = 0; rr < 128; rr += 2) {
    int r = rr + (t >> 7), m = t & 127;
    float v = ld1(W1, ((size_t)l*1536 + 512 + kt*128 + r)*MLPD + m, f32);
    sT[m*130 + r] = f2b(v);
  }
  __syncthreads();
  // write rows of W1T (coalesced over k)
  for (int mm = 0; mm < 128; mm += 2) {
    int m = mm + (t >> 7), kk = t & 127;
    W1T[((size_t)l*256 + path*128 + m)*1024 + kt*128 + kk] = sT[m*130 + kk];
  }
}

// ---------------- base accumulation (x part of encoder layer 1) ----------------
__global__ void k_base_acc(const void* __restrict__ x, const void* __restrict__ eaW1,
                           const void* __restrict__ egW1, const int* __restrict__ dflag,
                           float* __restrict__ baseacc) {
  const bool f32 = dflag[0] != 0;
  int l = blockIdx.x, path = blockIdx.y, kc = blockIdx.z, m = threadIdx.x; // 128 thr
  const void* W1 = path ? egW1 : eaW1;
  float acc = 0.0f;
  int i0 = kc*128;
  for (int i = i0; i < i0 + 128; ++i)
    acc += ld1(x, i, f32) * ld1(W1, ((size_t)l*1536 + i)*MLPD + m, f32);
  atomicAdd(&baseacc[path*512 + l*MLPD + m], acc);
}

// ---------------- MFMA k_z: Z = relu(base + b1 + H @ W1T^T) ----------------
// A = H [4096,1024] (dual), B = W1T [l][256][1024] bf16 (NT). Tile 64x64, 4 waves 2x2.
#define LPAD 40
__global__ __launch_bounds__(256) void k_z_mfma(
    const void* __restrict__ H, const u16* __restrict__ W1T,
    const void* __restrict__ eab1, const void* __restrict__ egb1,
    const float* __restrict__ baseacc, const int* __restrict__ dflag,
    u16* __restrict__ Z) {
  const bool f32 = dflag[0] != 0;
  __shared__ u16 sA[64*LPAD];
  __shared__ u16 sB[64*LPAD];
  int t = threadIdx.x;
  int row0 = blockIdx.x * 64;
  int n0   = blockIdx.y * 64;          // 0,64,128,192
  int l    = row0 >> 10;
  int wid = t >> 6, lane = t & 63;
  int waveM = wid >> 1, waveN = wid & 1;
  int quad = lane >> 4, lcol = lane & 15;
  int arow = t >> 2, kq = (t & 3) * 8;

  f32x4 acc[2][2];
  const f32x4 zz = {0.0f,0.0f,0.0f,0.0f};
#pragma unroll
  for (int i = 0; i < 2; ++i)
#pragma unroll
    for (int j = 0; j < 2; ++j) acc[i][j] = zz;

  size_t habase = (size_t)(row0 + arow)*HID;
  const u16* Bb = W1T + ((size_t)l*256 + n0 + arow)*1024;

  u16x8 av = ldc8(H, habase + kq, f32);                       // FIX: + kq
  u16x8 bv = *reinterpret_cast<const u16x8*>(Bb + kq);        // FIX: + kq
  for (int k0 = 0; k0 < HID; k0 += 32) {
    __syncthreads();
    *reinterpret_cast<u16x8*>(&sA[arow*LPAD + kq]) = av;
    *reinterpret_cast<u16x8*>(&sB[arow*LPAD + kq]) = bv;
    __syncthreads();
    if (k0 + 32 < HID) {
      av = ldc8(H, habase + k0 + 32 + kq, f32);
      bv = *reinterpret_cast<const u16x8*>(Bb + k0 + 32 + kq);
    }
    bf16x8 af[2];
#pragma unroll
    for (int i = 0; i < 2; ++i)
      af[i] = *reinterpret_cast<const bf16x8*>(&sA[(waveM*32 + i*16 + lcol)*LPAD + quad*8]);
#pragma unroll
    for (int j = 0; j < 2; ++j) {
      bf16x8 bf = *reinterpret_cast<const bf16x8*>(&sB[(waveN*32 + j*16 + lcol)*LPAD + quad*8]);
#pragma unroll
      for (int i = 0; i < 2; ++i)
        acc[i][j] = __builtin_amdgcn_mfma_f32_16x16x32_bf16(af[i], bf, acc[i][j], 0, 0, 0);
    }
  }
  // epilogue: + base + b1, relu, store
#pragma unroll
  for (int j = 0; j < 2; ++j) {
    int nn = n0 + waveN*32 + j*16 + lcol;
    int path = nn >> 7, m = nn & 127;
    float bval = baseacc[path*512 + l*MLPD + m] +
                 ld1(path ? egb1 : eab1, l*MLPD + m, f32);
#pragma unroll
    for (int i = 0; i < 2; ++i)
#pragma unroll
      for (int g = 0; g < 4; ++g) {
        int r = row0 + waveM*32 + i*16 + quad*4 + g;
        float v = acc[i][j][g] + bval;
        Z[(size_t)r*256 + nn] = f2b(v > 0.0f ? v : 0.0f);
      }
  }
}

// ---------------- VALU k_out (small): OUT = Za@W2a - Zg@W2g + bias diff ----------------
#define BM 64
#define BN 64
#define BK 16
__global__ __launch_bounds__(256) void k_out(
    const u16* __restrict__ Zb, const void* __restrict__ eaW2, const void* __restrict__ egW2,
    const void* __restrict__ eab2, const void* __restrict__ egb2,
    const int* __restrict__ dflag, u16* __restrict__ OUTT) {
  const bool f32 = dflag[0] != 0;
  __shared__ float As[BK][BM];
  __shared__ float Bs[BK][BN];
  int t = threadIdx.x;
  int row0 = blockIdx.x * BM;
  int n0   = blockIdx.y * BN;          // 0..448
  int l    = row0 >> 10;
  const u16* Ab = Zb + (size_t)row0 * 256;
  int tx = t & 15, ty = t >> 4;
  int am = t >> 2, akq = (t & 3) * 4;
  int bk = t >> 4, bn = (t & 15) * 4;

  float acc[4][4];
#pragma unroll
  for (int j = 0; j < 4; ++j) {
    int o = n0 + tx*4 + j;
    float bd = ld1(eab2, l*OUTD + o, f32) - ld1(egb2, l*OUTD + o, f32);
#pragma unroll
    for (int i = 0; i < 4; ++i) acc[i][j] = bd;
  }
  for (int ph = 0; ph < 2; ++ph) {
    const void* B = ph ? egW2 : eaW2;
    size_t boff = (size_t)l*MLPD*OUTD + n0;
    float sgn = ph ? -1.0f : 1.0f;
    for (int k0 = 0; k0 < MLPD; k0 += BK) {
      ushort4 avu = *reinterpret_cast<const ushort4*>(Ab + (size_t)am*256 + ph*128 + k0 + akq);
      F4 bvf = ld4(B, boff + (size_t)(k0 + bk)*OUTD + bn, f32);
      __syncthreads();
      As[akq+0][am] = b2f(avu.x); As[akq+1][am] = b2f(avu.y);
      As[akq+2][am] = b2f(avu.z); As[akq+3][am] = b2f(avu.w);
      Bs[bk][bn+0] = sgn*bvf.x; Bs[bk][bn+1] = sgn*bvf.y;
      Bs[bk][bn+2] = sgn*bvf.z; Bs[bk][bn+3] = sgn*bvf.w;
      __syncthreads();
#pragma unroll
      for (int kk = 0; kk < BK; ++kk) {
        float4 a4 = *reinterpret_cast<const float4*>(&As[kk][ty*4]);
        float4 b4 = *reinterpret_cast<const float4*>(&Bs[kk][tx*4]);
        float a[4] = {a4.x,a4.y,a4.z,a4.w};
        float b[4] = {b4.x,b4.y,b4.z,b4.w};
#pragma unroll
        for (int i = 0; i < 4; ++i)
#pragma unroll
          for (int j = 0; j < 4; ++j) acc[i][j] += a[i]*b[j];
      }
    }
  }
#pragma unroll
  for (int i = 0; i < 4; ++i) {
    int r = row0 + ty*4 + i;
#pragma unroll
    for (int j = 0; j < 4; ++j)
      OUTT[(size_t)r*KP + n0 + tx*4 + j] = f2b(acc[i][j]);
  }
}

// tension -> OUTT col 512 (bf16); zero pad cols 513..543; tsum += sumsq(row)
__global__ void k_tension(u16* __restrict__ OUTT, float* __restrict__ tsum) {
  int row = blockIdx.x, t = threadIdx.x;
  u16* p = OUTT + (size_t)row*KP;
  float v0 = b2f(p[t]), v1 = b2f(p[t+256]);
  float s = v0*v0 + v1*v1;
#pragma unroll
  for (int off = 32; off > 0; off >>= 1) s += __shfl_down(s, off, 64);
  __shared__ float red[4];
  if ((t & 63) == 0) red[t >> 6] = s;
  __syncthreads();
  if (t == 0) {
    float tot = red[0] + red[1] + red[2] + red[3];
    p[512] = f2b(tot * (1.0f/512.0f));
    atomicAdd(tsum, tot);
  }
  if (t < 31) p[513 + t] = 0;
}

// ---------------- fused MFMA GRU (XCD-swizzled, prefetched) ----------------
__global__ __launch_bounds__(256) void k_gru_mfma(
    const u16* __restrict__ OUTT, const void* __restrict__ H,
    const u16* __restrict__ WihP, const void* __restrict__ Whh,
    const float* __restrict__ bs_r, const float* __restrict__ bs_z,
    const float* __restrict__ bn_i, const float* __restrict__ bn_h,
    const int* __restrict__ dflag, void* __restrict__ outv) {
  const bool f32 = dflag[0] != 0;
  __shared__ u16 sA[64*LPAD];
  __shared__ u16 sB[3][64*LPAD];
  int t = threadIdx.x;
  // XCD swizzle: bid%8 -> (rowGroup=l, jGroup); each B slab lives on one XCD.
  int bid = blockIdx.x;            // 0..1023
  int xg = bid & 7;
  int inner = bid >> 3;            // 0..127
  int rowGroup = xg & 3;           // == l
  int jGroup = xg >> 2;            // 0..1
  int row0 = (rowGroup*16 + (inner & 15)) * 64;
  int j0   = (jGroup*8 + (inner >> 4)) * 64;
  int l    = row0 >> 10;
  int wid = t >> 6, lane = t & 63;
  int waveM = wid >> 1, waveN = wid & 1;
  int quad = lane >> 4, lcol = lane & 15;
  int arow = t >> 2, kq = (t & 3) * 8;

  f32x4 acc[4][2][2];   // bands r,z,i_n,h_n
  const f32x4 zz = {0.0f,0.0f,0.0f,0.0f};
#pragma unroll
  for (int b = 0; b < 4; ++b)
#pragma unroll
    for (int i = 0; i < 2; ++i)
#pragma unroll
      for (int j = 0; j < 2; ++j) acc[b][i][j] = zz;

  // ---- GEMM1: gi over K=544 (pure bf16) ----
  {
    const u16* Ab = OUTT + (size_t)(row0 + arow) * KP;
    const u16* Bb = WihP + ((size_t)l * G3 + j0 + arow) * KP;
    u16x8 av = *reinterpret_cast<const u16x8*>(Ab + kq);
    u16x8 bv[3];
#pragma unroll
    for (int b = 0; b < 3; ++b)
      bv[b] = *reinterpret_cast<const u16x8*>(Bb + (size_t)b*1024*KP + kq);
    for (int k0 = 0; k0 < KP; k0 += 32) {
      __syncthreads();
      *reinterpret_cast<u16x8*>(&sA[arow*LPAD + kq]) = av;
#pragma unroll
      for (int b = 0; b < 3; ++b)
        *reinterpret_cast<u16x8*>(&sB[b][arow*LPAD + kq]) = bv[b];
      __syncthreads();
      if (k0 + 32 < KP) {
        av = *reinterpret_cast<const u16x8*>(Ab + k0 + 32 + kq);
#pragma unroll
        for (int b = 0; b < 3; ++b)
          bv[b] = *reinterpret_cast<const u16x8*>(Bb + (size_t)b*1024*KP + k0 + 32 + kq);
      }
      bf16x8 af[2];
#pragma unroll
      for (int i = 0; i < 2; ++i)
        af[i] = *reinterpret_cast<const bf16x8*>(&sA[(waveM*32 + i*16 + lcol)*LPAD + quad*8]);
#pragma unroll
      for (int b = 0; b < 3; ++b)
#pragma unroll
        for (int j = 0; j < 2; ++j) {
          bf16x8 bf = *reinterpret_cast<const bf16x8*>(
              &sB[b][(waveN*32 + j*16 + lcol)*LPAD + quad*8]);
#pragma unroll
          for (int i = 0; i < 2; ++i)
            acc[b][i][j] = __builtin_amdgcn_mfma_f32_16x16x32_bf16(af[i], bf, acc[b][i][j], 0, 0, 0);
        }
    }
  }
  // ---- GEMM2: gh over K=1024 (dual-dtype converted on stage) ----
  {
    size_t hbase = (size_t)(row0 + arow) * HID;
    size_t wbase = ((size_t)l * G3 + j0 + arow) * HID;
    u16x8 av = ldc8(H, hbase + kq, f32);
    u16x8 bv[3];
#pragma unroll
    for (int b = 0; b < 3; ++b)
      bv[b] = ldc8(Whh, wbase + (size_t)b*1024*HID + kq, f32);
    for (int k0 = 0; k0 < HID; k0 += 32) {
      __syncthreads();
      *reinterpret_cast<u16x8*>(&sA[arow*LPAD + kq]) = av;
#pragma unroll
      for (int b = 0; b < 3; ++b)
        *reinterpret_cast<u16x8*>(&sB[b][arow*LPAD + kq]) = bv[b];
      __syncthreads();
      if (k0 + 32 < HID) {
        av = ldc8(H, hbase + k0 + 32 + kq, f32);
#pragma unroll
        for (int b = 0; b < 3; ++b)
          bv[b] = ldc8(Whh, wbase + (size_t)b*1024*HID + k0 + 32 + kq, f32);
      }
      bf16x8 af[2];
#pragma unroll
      for (int i = 0; i < 2; ++i)
        af[i] = *reinterpret_cast<const bf16x8*>(&sA[(waveM*32 + i*16 + lcol)*LPAD + quad*8]);
#pragma unroll
      for (int b = 0; b < 3; ++b) {
        int ai = (b < 2) ? b : 3;
#pragma unroll
        for (int j = 0; j < 2; ++j) {
          bf16x8 bf = *reinterpret_cast<const bf16x8*>(
              &sB[b][(waveN*32 + j*16 + lcol)*LPAD + quad*8]);
#pragma unroll
          for (int i = 0; i < 2; ++i)
            acc[ai][i][j] = __builtin_amdgcn_mfma_f32_16x16x32_bf16(af[i], bf, acc[ai][i][j], 0, 0, 0);
        }
      }
    }
  }
  // ---- epilogue: gates -> new_h into d_out hh region ----
#pragma unroll
  for (int i = 0; i < 2; ++i)
#pragma unroll
    for (int j = 0; j < 2; ++j) {
      int jj = j0 + waveN*32 + j*16 + lcol;
      float br = bs_r[l*HID + jj], bz = bs_z[l*HID + jj];
      float bi = bn_i[l*HID + jj], bh = bn_h[l*HID + jj];
#pragma unroll
      for (int g = 0; g < 4; ++g) {
        int r = row0 + waveM*32 + i*16 + quad*4 + g;
        float rg = sigm(acc[0][i][j][g] + br);
        float zg = sigm(acc[1][i][j][g] + bz);
        float ng = tanhf(acc[2][i][j][g] + bi + rg*(acc[3][i][j][g] + bh));
        float hv = ld1(H, (size_t)r*HID + jj, f32);
        st1(outv, 513 + (size_t)r*HID + jj, (1.0f - zg)*ng + zg*hv, f32);
      }
    }
}

// ---------------- level means (split-C atomics) ----------------
__global__ void k_lm_acc(const void* __restrict__ outv, const int* __restrict__ dflag,
                         float* __restrict__ lm) {
  const bool f32 = dflag[0] != 0;
  int l = blockIdx.x, cc = blockIdx.y, t = threadIdx.x;
  float s0=0.f, s1=0.f, s2=0.f, s3=0.f;
  for (int c = cc*64; c < cc*64 + 64; ++c) {
    size_t base = 513 + (size_t)(l*CPL + c)*HID;
    s0 += ld1(outv, base + t,       f32);
    s1 += ld1(outv, base + 256 + t, f32);
    s2 += ld1(outv, base + 512 + t, f32);
    s3 += ld1(outv, base + 768 + t, f32);
  }
  atomicAdd(&lm[l*HID + t],       s0);
  atomicAdd(&lm[l*HID + 256 + t], s1);
  atomicAdd(&lm[l*HID + 512 + t], s2);
  atomicAdd(&lm[l*HID + 768 + t], s3);
}
__global__ void k_lmfin(float* __restrict__ lm) {
  int idx = blockIdx.x*256 + threadIdx.x;
  lm[idx] *= (1.0f/1024.0f);
}

// ---------------- predictors (split-K atomics) ----------------
__global__ void k_pz_acc(const float* __restrict__ lm, const void* __restrict__ pW1,
                         const int* __restrict__ dflag, float* __restrict__ pz) {
  const bool f32 = dflag[0] != 0;
  int lv = blockIdx.x, mb = blockIdx.y, kc = blockIdx.z;
  int m = mb*256 + threadIdx.x;
  float acc = 0.0f;
  int i0 = kc*128;
  const float* lmp = lm + (lv + 1)*HID;
  for (int i = i0; i < i0 + 128; ++i)
    acc += lmp[i] * ld1(pW1, ((size_t)lv*HID + i)*HID + m, f32);
  atomicAdd(&pz[lv*HID + m], acc);
}
__global__ void k_pzfin(float* __restrict__ pz, const void* __restrict__ pb1,
                        const int* __restrict__ dflag) {
  const bool f32 = dflag[0] != 0;
  int idx = blockIdx.x*256 + threadIdx.x;   // [0,3072)
  float v = pz[idx] + ld1(pb1, idx, f32);
  pz[idx] = v > 0.0f ? v : 0.0f;
}
__global__ void k_pe_acc(const float* __restrict__ pz, const void* __restrict__ pW2,
                         const int* __restrict__ dflag, float* __restrict__ pe) {
  const bool f32 = dflag[0] != 0;
  int lv = blockIdx.x, ob = blockIdx.y, kc = blockIdx.z;
  int o = ob*256 + threadIdx.x;
  float acc = 0.0f;
  int m0 = kc*128;
  const float* pzp = pz + lv*HID;
  for (int m = m0; m < m0 + 128; ++m)
    acc += pzp[m] * ld1(pW2, ((size_t)lv*HID + m)*HID + o, f32);
  atomicAdd(&pe[lv*HID + o], acc);
}
__global__ void k_pefin(float* __restrict__ pe, const void* __restrict__ pb2,
                        const float* __restrict__ lm, const int* __restrict__ dflag) {
  const bool f32 = dflag[0] != 0;
  int idx = blockIdx.x*256 + threadIdx.x;   // [0,3072)
  pe[idx] = (pe[idx] + ld1(pb2, idx, f32) - lm[idx]) * 0.05f;
}

__global__ void k_addc_gop(const float* __restrict__ lm, const float* __restrict__ pe,
                           float* __restrict__ addc, float* __restrict__ gop) {
  int j = blockIdx.x*256 + threadIdx.x;
  float pe0 = pe[j], pe1 = pe[1024 + j], pe2 = pe[2048 + j];
  float d0 = pe0, d1 = pe1 - 0.5f*pe0, d2 = pe2 - 0.5f*pe1, d3 = -0.5f*pe2;
  float l0 = lm[j], l1 = lm[1024 + j], l2 = lm[2048 + j], l3 = lm[3072 + j];
  addc[j]        = 0.2775f*l0 + d0;
  addc[1024 + j] = 0.2775f*l1 + d1;
  addc[2048 + j] = 0.2775f*l2 + d2;
  addc[3072 + j] = 0.2775f*l3 + d3;
  gop[j] = 0.25f*((l0 + d0) + (l1 + d1) + (l2 + d2) + (l3 + d3));
}

__global__ void k_comb_acc(const float* __restrict__ lm, const void* __restrict__ peiW,
                           const int* __restrict__ dflag, float* __restrict__ comb) {
  const bool f32 = dflag[0] != 0;
  int ob = blockIdx.x, kc = blockIdx.y;
  int o = ob*256 + threadIdx.x;
  float acc = 0.0f;
  int i0 = kc*256;
  for (int i = i0; i < i0 + 256; ++i)
    acc += lm[i] * ld1(peiW, (size_t)i*OUTD + o, f32);
  atomicAdd(&comb[o], acc);
}
__global__ void k_fin(const float* __restrict__ comb, const void* __restrict__ peib,
                      const float* __restrict__ tsum, const int* __restrict__ dflag,
                      void* __restrict__ outv) {
  const bool f32 = dflag[0] != 0;
  int o = blockIdx.x*256 + threadIdx.x;
  st1(outv, o, comb[o] + ld1(peib, o, f32), f32);
  if (o == 0) st1(outv, 512, tsum[0] * (1.0f/(4096.0f*512.0f)), f32);
}

__global__ void k_hh(void* __restrict__ outv, const float* __restrict__ addc,
                     const float* __restrict__ gop, const int* __restrict__ step,
                     const int* __restrict__ dflag) {
  const bool f32 = dflag[0] != 0;
  int row = blockIdx.x, t = threadIdx.x;
  int l = row >> 10, c = row & 1023;
  bool debate = (step[0] > 5) && (c < 256);
  size_t base = 513 + (size_t)row*HID;
#pragma unroll
  for (int k = 0; k < 4; ++k) {
    int j = t + k*256;
    float v = 0.7225f * ld1(outv, base + j, f32) + addc[l*HID + j];
    if (debate) v = 0.85f*v + 0.15f*gop[j];
    st1(outv, base + j, v, f32);
  }
}

extern "C" void kernel_launch(void* const* d_in, const int* in_sizes, int n_in,
                              void* d_out, int out_size, void* d_ws, size_t ws_size,
                              hipStream_t stream) {
  (void)in_sizes; (void)n_in; (void)out_size; (void)ws_size;
  const void* x    = d_in[0];
  const void* hid  = d_in[1];
  const void* eaW1 = d_in[2];
  const void* eab1 = d_in[3];
  const void* eaW2 = d_in[4];
  const void* eab2 = d_in[5];
  const void* egW1 = d_in[6];
  const void* egb1 = d_in[7];
  const void* egW2 = d_in[8];
  const void* egb2 = d_in[9];
  const void* gWih = d_in[10];
  const void* gWhh = d_in[11];
  const void* gbih = d_in[12];
  const void* gbhh = d_in[13];
  const void* pW1  = d_in[14];
  const void* pb1  = d_in[15];
  const void* pW2  = d_in[16];
  const void* pb2  = d_in[17];
  const void* peiW = d_in[18];
  const void* peib = d_in[19];
  const int*  step = (const int*)d_in[20];

  // ---- workspace layout (~20.06 MB, proven size) ----
  float* wsf = (float*)d_ws;
  float* tsum    = wsf + 0;       // 64
  float* baseacc = wsf + 64;      // 1024
  float* lm      = wsf + 1088;    // 4096
  float* pz      = wsf + 5184;    // 3072
  float* pe      = wsf + 8256;    // 3072
  float* comb    = wsf + 11328;   // 512 (+pad to 12288)
  int*   dflag   = (int*)(wsf + 12288);  // 64
  float* bs_r    = wsf + 12352;   // 4096
  float* bs_z    = wsf + 16448;   // 4096
  float* bn_i    = wsf + 20544;   // 4096
  float* bn_h    = wsf + 24640;   // 4096
  float* addc    = wsf + 28736;   // 4096
  float* gop     = wsf + 32832;   // 1024
  u16* Zb   = (u16*)(wsf + 33856);        // 4096*256
  u16* OUTT = Zb + (size_t)4096*256;      // 4096*544
  u16* WihP = OUTT + (size_t)4096*KP;     // 12288*544
  // W1T (4*256*1024 u16 = 2.1 MB) overlays OUTT: dead once k_z finishes,
  // before k_out writes OUTT.
  u16* W1T  = OUTT;

  k_detect   <<<dim3(1),        dim3(256), 0, stream>>>(x, dflag);
  k_prep     <<<dim3(64),       dim3(256), 0, stream>>>(wsf, gbih, gbhh, dflag,
                                                        bs_r, bs_z, bn_i, bn_h);
  k_prep_wih <<<dim3(12288),    dim3(256), 0, stream>>>(gWih, dflag, WihP);
  k_prep_w1t <<<dim3(4,2,8),    dim3(256), 0, stream>>>(eaW1, egW1, dflag, W1T);
  k_base_acc <<<dim3(4,2,4),    dim3(128), 0, stream>>>(x, eaW1, egW1, dflag, baseacc);
  k_z_mfma   <<<dim3(64,4),     dim3(256), 0, stream>>>(hid, W1T, eab1, egb1,
                                                        baseacc, dflag, Zb);
  k_out      <<<dim3(64,8),     dim3(256), 0, stream>>>(Zb, eaW2, egW2, eab2, egb2,
                                                        dflag, OUTT);
  k_tension  <<<dim3(4096),     dim3(256), 0, stream>>>(OUTT, tsum);
  k_gru_mfma <<<dim3(1024),     dim3(256), 0, stream>>>(OUTT, hid, WihP, gWhh,
                                                        bs_r, bs_z, bn_i, bn_h,
                                                        dflag, d_out);
  k_lm_acc   <<<dim3(4,16),     dim3(256), 0, stream>>>(d_out, dflag, lm);
  k_lmfin    <<<dim3(16),       dim3(256), 0, stream>>>(lm);
  k_pz_acc   <<<dim3(3,4,8),    dim3(256), 0, stream>>>(lm, pW1, dflag, pz);
  k_pzfin    <<<dim3(12),       dim3(256), 0, stream>>>(pz, pb1, dflag);
  k_pe_acc   <<<dim3(3,4,8),    dim3(256), 0, stream>>>(pz, pW2, dflag, pe);
  k_pefin    <<<dim3(12),       dim3(256), 0, stream>>>(pe, pb2, lm, dflag);
  k_addc_gop <<<dim3(4),        dim3(256), 0, stream>>>(lm, pe, addc, gop);
  k_comb_acc <<<dim3(2,16),     dim3(256), 0, stream>>>(lm, peiW, dflag, comb);
  k_fin      <<<dim3(2),        dim3(256), 0, stream>>>(comb, peib, tsum, dflag, d_out);
  k_hh       <<<dim3(4096),     dim3(256), 0, stream>>>(d_out, addc, gop, step, dflag);
}